// Round 1
// baseline (659.125 us; speedup 1.0000x reference)
//
#include <hip/hip_runtime.h>
#include <hip/hip_bf16.h>

// Problem constants
#define BATCH 32
#define HH 56
#define WWD 56
#define CIN 192
#define NH 6
#define HD 32
#define WSZ 7
#define NWH 8          // windows per side
#define NW 64          // windows per image
#define NT 49          // tokens per window
#define PIX_PER_B 3136 // NW*NT = 56*56
#define M_TOTAL (BATCH * PIX_PER_B) // 100352
#define QKV_N 576
#define SCALE 0.17677669529663687f

__device__ __forceinline__ float bf2f(unsigned short s) {
    return __uint_as_float(((unsigned)s) << 16);
}
__device__ __forceinline__ unsigned short f2bf(float f) {
    __hip_bfloat16 h = __float2bfloat16(f);
    return *reinterpret_cast<unsigned short*>(&h);
}

// ---------------------------------------------------------------------------
// Kernel A: fused roll(-3,-3) + QKV GEMM.
// A = x (rows in windowed order, gathered with roll), B = w_qkv (576x192).
// Out: q,k,v bf16, each laid out [B][NH][nw][n][HD].
// Tiles: BM=64, BN=64, BK=16. 256 threads, 4x4 micro-tile each.
// ---------------------------------------------------------------------------
__global__ __launch_bounds__(256) void qkv_gemm(
        const float* __restrict__ x, const float* __restrict__ wqkv,
        __hip_bfloat16* __restrict__ qo, __hip_bfloat16* __restrict__ ko,
        __hip_bfloat16* __restrict__ vo) {
    __shared__ float As[16][68];
    __shared__ float Bs[16][68];
    const int tid = threadIdx.x;
    const int col0 = blockIdx.x * 64;
    const int row0 = blockIdx.y * 64;

    const int lm = tid >> 2;         // 0..63: tile row (A) / tile col (B)
    const int lk4 = (tid & 3) * 4;   // 0,4,8,12

    // Source pixel for A row r = row0+lm (windowed order, with roll -3,-3)
    const int r = row0 + lm;
    const int b = r / PIX_PER_B;
    const int rem = r % PIX_PER_B;          // w*49 + i
    const int w = rem / NT;
    const int i = rem % NT;
    const int yi = i / WSZ, xi = i % WSZ;
    const int h = (w >> 3) * WSZ + yi;      // rolled coords
    const int wc = (w & 7) * WSZ + xi;
    const int sh = (h + 3) % HH;
    const int sw = (wc + 3) % WWD;
    const float* arow = x + ((size_t)(b * HH + sh) * WWD + sw) * CIN;
    const float* brow = wqkv + (size_t)(col0 + lm) * CIN;

    const int ty = tid >> 4;   // 0..15 -> rows ty*4..ty*4+3
    const int tx = tid & 15;   // 0..15 -> cols tx*4..tx*4+3

    float acc[4][4];
#pragma unroll
    for (int a_ = 0; a_ < 4; a_++)
#pragma unroll
        for (int b_ = 0; b_ < 4; b_++) acc[a_][b_] = 0.f;

    for (int k0 = 0; k0 < CIN; k0 += 16) {
        float4 av = *(const float4*)(arow + k0 + lk4);
        float4 bv = *(const float4*)(brow + k0 + lk4);
        __syncthreads();
        As[lk4 + 0][lm] = av.x; As[lk4 + 1][lm] = av.y;
        As[lk4 + 2][lm] = av.z; As[lk4 + 3][lm] = av.w;
        Bs[lk4 + 0][lm] = bv.x; Bs[lk4 + 1][lm] = bv.y;
        Bs[lk4 + 2][lm] = bv.z; Bs[lk4 + 3][lm] = bv.w;
        __syncthreads();
#pragma unroll
        for (int kk = 0; kk < 16; kk++) {
            float4 a4 = *(const float4*)&As[kk][ty * 4];
            float4 b4 = *(const float4*)&Bs[kk][tx * 4];
            float av_[4] = {a4.x, a4.y, a4.z, a4.w};
            float bv_[4] = {b4.x, b4.y, b4.z, b4.w};
#pragma unroll
            for (int ii = 0; ii < 4; ii++)
#pragma unroll
                for (int jj = 0; jj < 4; jj++) acc[ii][jj] += av_[ii] * bv_[jj];
        }
    }

    // Store: split 576 cols into q/k/v, head-major bf16 layout
    const int c = col0 + tx * 4;
    const int part = c / 192;
    const int head = (c % 192) >> 5;
    const int d0 = c & 31;
    __hip_bfloat16* dst = (part == 0) ? qo : (part == 1) ? ko : vo;
#pragma unroll
    for (int ii = 0; ii < 4; ii++) {
        const int r2 = row0 + ty * 4 + ii;
        const int b2 = r2 / PIX_PER_B;
        const int rem2 = r2 % PIX_PER_B;
        size_t idx = ((size_t)(b2 * NH + head) * PIX_PER_B + rem2) * HD + d0;
        ushort4 st;
        st.x = f2bf(acc[ii][0]); st.y = f2bf(acc[ii][1]);
        st.z = f2bf(acc[ii][2]); st.w = f2bf(acc[ii][3]);
        *reinterpret_cast<ushort4*>(dst + idx) = st;
    }
}

// ---------------------------------------------------------------------------
// Kernel B: per-(batch, head, window) attention.
// dots = q k^T * scale + bias + mask; softmax; out = attn @ v.
// Writes aout in pixel-major (rolled) layout [B][nw][n][NH*HD] bf16.
// ---------------------------------------------------------------------------
__global__ __launch_bounds__(256) void attn_kernel(
        const __hip_bfloat16* __restrict__ qg, const __hip_bfloat16* __restrict__ kg,
        const __hip_bfloat16* __restrict__ vg, const float* __restrict__ pe,
        __hip_bfloat16* __restrict__ aout) {
    const int bx = blockIdx.x;
    const int w = bx & 63;
    const int head = (bx >> 6) % NH;
    const int b = bx / (NH * NW);

    __shared__ float qs[49][36];
    __shared__ float ks[49][36];
    __shared__ float vs[49][36];
    __shared__ float ds[49][51];
    __shared__ float pes[169];
    __shared__ float rinv[49];

    const int t = threadIdx.x;
    const size_t base = ((size_t)(b * NH + head) * PIX_PER_B + (size_t)w * NT) * HD;

    if (t < 196) {
        const int j = t >> 2;
        const int d0 = (t & 3) * 8;
        const uint4 qv = *(const uint4*)((const unsigned short*)qg + base + j * HD + d0);
        const uint4 kv = *(const uint4*)((const unsigned short*)kg + base + j * HD + d0);
        const uint4 vv = *(const uint4*)((const unsigned short*)vg + base + j * HD + d0);
        const uint qa[4] = {qv.x, qv.y, qv.z, qv.w};
        const uint ka[4] = {kv.x, kv.y, kv.z, kv.w};
        const uint va[4] = {vv.x, vv.y, vv.z, vv.w};
#pragma unroll
        for (int e = 0; e < 4; e++) {
            qs[j][d0 + 2 * e] = bf2f((unsigned short)(qa[e] & 0xffff));
            qs[j][d0 + 2 * e + 1] = bf2f((unsigned short)(qa[e] >> 16));
            ks[j][d0 + 2 * e] = bf2f((unsigned short)(ka[e] & 0xffff));
            ks[j][d0 + 2 * e + 1] = bf2f((unsigned short)(ka[e] >> 16));
            vs[j][d0 + 2 * e] = bf2f((unsigned short)(va[e] & 0xffff));
            vs[j][d0 + 2 * e + 1] = bf2f((unsigned short)(va[e] >> 16));
        }
    }
    if (t < 169) pes[t] = pe[t];
    __syncthreads();

    // dots phase: thread t<245 owns row i = t%49, j-chunks c = t/49, t/49+5, ...
    const bool ulm = ((w >> 3) == 7);
    const bool lrm = ((w & 7) == 7);
    if (t < 245) {
        const int i = t % 49;
        const int jc = t / 49;
        const int yi = i / 7, xi = i % 7;
        float qreg[32];
#pragma unroll
        for (int d4 = 0; d4 < 8; d4++) {
            float4 q4 = *(const float4*)&qs[i][d4 * 4];
            qreg[4 * d4 + 0] = q4.x; qreg[4 * d4 + 1] = q4.y;
            qreg[4 * d4 + 2] = q4.z; qreg[4 * d4 + 3] = q4.w;
        }
        for (int c = jc; c < 13; c += 5) {
            const int j0 = c * 4;
#pragma unroll
            for (int jj = 0; jj < 4; jj++) {
                const int j = j0 + jj;
                if (j < 49) {
                    float acc = 0.f;
#pragma unroll
                    for (int d4 = 0; d4 < 8; d4++) {
                        float4 k4 = *(const float4*)&ks[j][d4 * 4];
                        acc += qreg[4 * d4 + 0] * k4.x + qreg[4 * d4 + 1] * k4.y +
                               qreg[4 * d4 + 2] * k4.z + qreg[4 * d4 + 3] * k4.w;
                    }
                    const int yj = j / 7, xj = j % 7;
                    float val = acc * SCALE + pes[(yj - yi + 6) * 13 + (xj - xi + 6)];
                    if (ulm && ((yi >= 4) != (yj >= 4))) val = -1e30f;
                    if (lrm && ((xi >= 4) != (xj >= 4))) val = -1e30f;
                    ds[i][j] = val;
                }
            }
        }
    }
    __syncthreads();

    // softmax per row
    if (t < 49) {
        float mx = -1e30f;
#pragma unroll
        for (int j = 0; j < 49; j++) mx = fmaxf(mx, ds[t][j]);
        float s = 0.f;
#pragma unroll
        for (int j = 0; j < 49; j++) {
            float e = __expf(ds[t][j] - mx);
            ds[t][j] = e;
            s += e;
        }
        rinv[t] = 1.0f / s;
    }
    __syncthreads();

    // PV: 49 rows x 8 float4-cols = 392 tasks
    for (int p = t; p < 392; p += 256) {
        const int i = p >> 3;
        const int d4 = p & 7;
        float ax = 0.f, ay = 0.f, az = 0.f, aw = 0.f;
        for (int j = 0; j < 49; j++) {
            const float a = ds[i][j];
            float4 v4 = *(const float4*)&vs[j][d4 * 4];
            ax += a * v4.x; ay += a * v4.y; az += a * v4.z; aw += a * v4.w;
        }
        const float ri = rinv[i];
        size_t o = ((size_t)b * PIX_PER_B + (size_t)w * NT + i) * CIN + head * HD + d4 * 4;
        ushort4 st;
        st.x = f2bf(ax * ri); st.y = f2bf(ay * ri);
        st.z = f2bf(az * ri); st.w = f2bf(aw * ri);
        *reinterpret_cast<ushort4*>((unsigned short*)aout + o) = st;
    }
}

// ---------------------------------------------------------------------------
// Kernel C: output projection GEMM + bias, fused with roll(+3,+3).
// Rows = final pixel order (b,h,w); A-row gathered from aout via inverse roll
// + window mapping. Out fp32 [B][H][W][192].
// ---------------------------------------------------------------------------
__global__ __launch_bounds__(256) void out_gemm(
        const __hip_bfloat16* __restrict__ aout, const float* __restrict__ wout,
        const float* __restrict__ bout, float* __restrict__ out) {
    __shared__ float As[16][68];
    __shared__ float Bs[16][68];
    const int tid = threadIdx.x;
    const int col0 = blockIdx.x * 64;
    const int row0 = blockIdx.y * 64;

    const int lm = tid >> 2;
    const int lk4 = (tid & 3) * 4;

    const int r = row0 + lm;
    const int b = r / PIX_PER_B;
    const int pix = r % PIX_PER_B;
    const int h = pix / WWD, wc = pix % WWD;
    const int hr = (h + 53) % HH;      // inverse roll (+3 final == read at -3)
    const int wr = (wc + 53) % WWD;
    const int wh = hr / WSZ, yi = hr % WSZ;
    const int ww = wr / WSZ, xi = wr % WSZ;
    const unsigned short* arow = (const unsigned short*)aout +
        ((size_t)b * PIX_PER_B + (size_t)(wh * NWH + ww) * NT + (yi * WSZ + xi)) * CIN;
    const float* brow = wout + (size_t)(col0 + lm) * CIN;

    const int ty = tid >> 4;
    const int tx = tid & 15;

    float acc[4][4];
#pragma unroll
    for (int a_ = 0; a_ < 4; a_++)
#pragma unroll
        for (int b_ = 0; b_ < 4; b_++) acc[a_][b_] = 0.f;

    for (int k0 = 0; k0 < CIN; k0 += 16) {
        ushort4 av = *(const ushort4*)(arow + k0 + lk4);
        float4 bv = *(const float4*)(brow + k0 + lk4);
        __syncthreads();
        As[lk4 + 0][lm] = bf2f(av.x); As[lk4 + 1][lm] = bf2f(av.y);
        As[lk4 + 2][lm] = bf2f(av.z); As[lk4 + 3][lm] = bf2f(av.w);
        Bs[lk4 + 0][lm] = bv.x; Bs[lk4 + 1][lm] = bv.y;
        Bs[lk4 + 2][lm] = bv.z; Bs[lk4 + 3][lm] = bv.w;
        __syncthreads();
#pragma unroll
        for (int kk = 0; kk < 16; kk++) {
            float4 a4 = *(const float4*)&As[kk][ty * 4];
            float4 b4 = *(const float4*)&Bs[kk][tx * 4];
            float av_[4] = {a4.x, a4.y, a4.z, a4.w};
            float bv_[4] = {b4.x, b4.y, b4.z, b4.w};
#pragma unroll
            for (int ii = 0; ii < 4; ii++)
#pragma unroll
                for (int jj = 0; jj < 4; jj++) acc[ii][jj] += av_[ii] * bv_[jj];
        }
    }

    const int c = col0 + tx * 4;
    const float4 bo = *(const float4*)(bout + c);
#pragma unroll
    for (int ii = 0; ii < 4; ii++) {
        const int r2 = row0 + ty * 4 + ii;
        float4 res;
        res.x = acc[ii][0] + bo.x; res.y = acc[ii][1] + bo.y;
        res.z = acc[ii][2] + bo.z; res.w = acc[ii][3] + bo.w;
        *reinterpret_cast<float4*>(out + (size_t)r2 * CIN + c) = res;
    }
}

// ---------------------------------------------------------------------------
extern "C" void kernel_launch(void* const* d_in, const int* in_sizes, int n_in,
                              void* d_out, int out_size, void* d_ws, size_t ws_size,
                              hipStream_t stream) {
    const float* x = (const float*)d_in[0];
    const float* wqkv = (const float*)d_in[1];
    const float* pe = (const float*)d_in[2];
    const float* wout = (const float*)d_in[3];
    const float* bout = (const float*)d_in[4];
    float* out = (float*)d_out;

    const size_t per = (size_t)BATCH * NH * PIX_PER_B * HD; // 19,267,584 elems
    __hip_bfloat16* q = (__hip_bfloat16*)d_ws;
    __hip_bfloat16* k = q + per;
    __hip_bfloat16* v = k + per;
    __hip_bfloat16* ao = v + per;
    (void)ws_size; (void)in_sizes; (void)n_in; (void)out_size;

    qkv_gemm<<<dim3(QKV_N / 64, M_TOTAL / 64), 256, 0, stream>>>(x, wqkv, q, k, v);
    attn_kernel<<<BATCH * NH * NW, 256, 0, stream>>>(q, k, v, pe, ao);
    out_gemm<<<dim3(CIN / 64, M_TOTAL / 64), 256, 0, stream>>>(ao, wout, bout, out);
}

// Round 2
// 299.277 us; speedup vs baseline: 2.2024x; 2.2024x over previous
//
#include <hip/hip_runtime.h>
#include <hip/hip_bf16.h>

#define PIX 3136
#define MTOT 100352
#define SCALE 0.17677669529663687f

typedef __attribute__((ext_vector_type(8))) short bf16x8;
typedef __attribute__((ext_vector_type(4))) float f32x4;
typedef __attribute__((ext_vector_type(8))) unsigned short u16x8;

__device__ __forceinline__ unsigned short f2bf(float f) {
    __hip_bfloat16 h = __float2bfloat16(f);
    return *reinterpret_cast<unsigned short*>(&h);
}

__device__ __forceinline__ u16x8 packbf(float4 a, float4 b) {
    u16x8 r;
    r[0] = f2bf(a.x); r[1] = f2bf(a.y); r[2] = f2bf(a.z); r[3] = f2bf(a.w);
    r[4] = f2bf(b.x); r[5] = f2bf(b.y); r[6] = f2bf(b.z); r[7] = f2bf(b.w);
    return r;
}

// ---------------------------------------------------------------------------
// Kernel A: fused roll(-3,-3) gather + fp32->bf16 + QKV GEMM via MFMA.
// Block: 256 thr (4 waves). BM=128, full K=192 in LDS, loop 9 N-tiles of 64.
// Per wave: 64x32 subtile (wr=wid>>1, wc=wid&1), A-frags hoisted to regs.
// LDS XOR-swizzle ((row&7)<<4) on both write and read.
// ---------------------------------------------------------------------------
__global__ __launch_bounds__(256) void qkv_mfma(
        const float* __restrict__ x, const float* __restrict__ wqkv,
        unsigned short* __restrict__ qo, unsigned short* __restrict__ ko,
        unsigned short* __restrict__ vo) {
    __shared__ __align__(16) unsigned char Al[128 * 384];
    __shared__ __align__(16) unsigned char Bl[64 * 384];
    const int tid = threadIdx.x;
    const int lane = tid & 63, wid = tid >> 6;
    const int G = lane >> 4, l16 = lane & 15;
    const int row0 = blockIdx.x * 128;

    // ---- stage A: gather rolled source row, convert to bf16, swizzled LDS ----
    {
        const int r = tid >> 1, half = tid & 1;
        const int gr = row0 + r;
        const int b = gr / PIX;
        const int rem = gr - b * PIX;
        const int w = rem / 49;
        const int i = rem - w * 49;
        const int yi = (i * 9363) >> 16;
        const int xi = i - yi * 7;
        int sh = (w >> 3) * 7 + yi + 3; if (sh >= 56) sh -= 56;
        int sw = (w & 7) * 7 + xi + 3; if (sw >= 56) sw -= 56;
        const float* src = x + ((size_t)(b * 56 + sh) * 56 + sw) * 192 + half * 96;
        const int swz = (r & 7) << 4;
#pragma unroll
        for (int c = 0; c < 12; c++) {
            float4 f0 = *(const float4*)(src + c * 8);
            float4 f1 = *(const float4*)(src + c * 8 + 4);
            const int off = half * 192 + c * 16;
            *(u16x8*)&Al[r * 384 + (off ^ swz)] = packbf(f0, f1);
        }
    }

    const int wr = wid >> 1, wc = wid & 1;
    f32x4 acc[4][2];
#pragma unroll
    for (int a = 0; a < 4; a++)
#pragma unroll
        for (int bb = 0; bb < 2; bb++) acc[a][bb] = (f32x4){0.f, 0.f, 0.f, 0.f};
    bf16x8 areg[4][6];

    for (int nt = 0; nt < 9; nt++) {
        __syncthreads();   // A ready (nt=0) / prev compute done reading Bl
        // ---- stage B tile: wqkv rows [nt*64, nt*64+64) fp32 -> bf16 ----
        {
            const int rB = tid >> 2, q4 = tid & 3;
            const float* src = wqkv + (size_t)(nt * 64 + rB) * 192 + q4 * 48;
            const int swz = (rB & 7) << 4;
#pragma unroll
            for (int c = 0; c < 6; c++) {
                float4 f0 = *(const float4*)(src + c * 8);
                float4 f1 = *(const float4*)(src + c * 8 + 4);
                const int off = q4 * 96 + c * 16;
                *(u16x8*)&Bl[rB * 384 + (off ^ swz)] = packbf(f0, f1);
            }
        }
        __syncthreads();
        if (nt == 0) {
#pragma unroll
            for (int mi = 0; mi < 4; mi++) {
                const int rr = wr * 64 + mi * 16 + l16;
                const int swz = (rr & 7) << 4;
#pragma unroll
                for (int ks = 0; ks < 6; ks++)
                    areg[mi][ks] = *(const bf16x8*)&Al[rr * 384 + ((ks * 64 + G * 16) ^ swz)];
            }
        }
#pragma unroll
        for (int ks = 0; ks < 6; ks++) {
#pragma unroll
            for (int ni = 0; ni < 2; ni++) {
                const int rb = wc * 32 + ni * 16 + l16;
                bf16x8 bf = *(const bf16x8*)&Bl[rb * 384 + ((ks * 64 + G * 16) ^ ((rb & 7) << 4))];
#pragma unroll
                for (int mi = 0; mi < 4; mi++)
                    acc[mi][ni] = __builtin_amdgcn_mfma_f32_16x16x32_bf16(
                        areg[mi][ks], bf, acc[mi][ni], 0, 0, 0);
            }
        }
        // ---- epilogue: store this N-tile as bf16 into q/k/v head-major ----
#pragma unroll
        for (int mi = 0; mi < 4; mi++) {
#pragma unroll
            for (int ni = 0; ni < 2; ni++) {
                const int nb = nt * 64 + wc * 32 + ni * 16;
                const int part = nb / 192;
                const int nn = nb - part * 192;
                const int head = nn >> 5;
                const int d = (nn & 31) + l16;
                unsigned short* dst = part == 0 ? qo : part == 1 ? ko : vo;
#pragma unroll
                for (int r = 0; r < 4; r++) {
                    const int rm = row0 + wr * 64 + mi * 16 + G * 4 + r;
                    const int b2 = rm / PIX;
                    const int rem2 = rm - b2 * PIX;
                    dst[((size_t)(b2 * 6 + head) * PIX + rem2) * 32 + d] = f2bf(acc[mi][ni][r]);
                    acc[mi][ni][r] = 0.f;
                }
            }
        }
    }
}

// ---------------------------------------------------------------------------
// Kernel B: attention, one wave per (b, head, window). 64x64 padded MFMA.
// QK^T (A=Q, B=K from global), bias+mask in C-layout, shfl row softmax,
// P->LDS (swizzled), V transposed in LDS, PV, write in FINAL pixel order.
// ---------------------------------------------------------------------------
__global__ __launch_bounds__(256) void attn_mfma(
        const unsigned short* __restrict__ qg, const unsigned short* __restrict__ kg,
        const unsigned short* __restrict__ vg, const float* __restrict__ pe,
        unsigned short* __restrict__ ao) {
    __shared__ float pes[169];
    __shared__ __align__(16) unsigned char Pl[4][8192];   // per-wave P 64x64 bf16
    __shared__ __align__(16) unsigned char Vl[4][4096];   // per-wave V^T 32x64 bf16
    const int tid = threadIdx.x, lane = tid & 63, wid = tid >> 6;
    const int G = lane >> 4, l16 = lane & 15;
    if (tid < 169) pes[tid] = pe[tid];

    const int gw = blockIdx.x * 4 + wid;
    const int b = gw / 384;
    const int r384 = gw - b * 384;
    const int head = r384 >> 6;
    const int w = r384 & 63;
    const int wh = w >> 3, ww = w & 7;

    // zero V^T (pad cols j>=49 must be 0, not junk)
#pragma unroll
    for (int z = 0; z < 4; z++)
        *(f32x4*)&Vl[wid][z * 1024 + lane * 16] = (f32x4){0.f, 0.f, 0.f, 0.f};

    const size_t base = ((size_t)(b * 6 + head) * PIX + w * 49) * 32;
    const unsigned short* qb = qg + base;
    const unsigned short* kb = kg + base;
    const unsigned short* vb = vg + base;

    // V transpose into LDS: vT[d][j], swizzled byte ^= ((d&7)<<4)
    for (int t = lane; t < 196; t += 64) {
        const int j = t >> 2, d0 = (t & 3) * 8;
        u16x8 vv = *(const u16x8*)(vb + j * 32 + d0);
#pragma unroll
        for (int e = 0; e < 8; e++) {
            const int d = d0 + e;
            *(unsigned short*)&Vl[wid][d * 128 + ((j * 2) ^ ((d & 7) << 4))] = vv[e];
        }
    }

    // Q (A-operand) and K (B-operand) fragments straight from global
    bf16x8 qf[4], kf[4];
    const bf16x8 zf = {0, 0, 0, 0, 0, 0, 0, 0};
#pragma unroll
    for (int mi = 0; mi < 4; mi++) {
        const int rr = mi * 16 + l16;
        qf[mi] = (rr < 49) ? *(const bf16x8*)(qb + rr * 32 + G * 8) : zf;
        kf[mi] = (rr < 49) ? *(const bf16x8*)(kb + rr * 32 + G * 8) : zf;
    }
    __syncthreads();   // pes ready

    const f32x4 zc = (f32x4){0.f, 0.f, 0.f, 0.f};
    f32x4 s[4][4];
#pragma unroll
    for (int mi = 0; mi < 4; mi++)
#pragma unroll
        for (int nj = 0; nj < 4; nj++)
            s[mi][nj] = __builtin_amdgcn_mfma_f32_16x16x32_bf16(qf[mi], kf[nj], zc, 0, 0, 0);

    // ---- bias + masks + row softmax (rows i live in fixed lanes) ----
    const bool ulm = (wh == 7), lrm = (ww == 7);
    int jv[4], yj[4], xj[4];
#pragma unroll
    for (int nj = 0; nj < 4; nj++) {
        jv[nj] = nj * 16 + l16;
        yj[nj] = (jv[nj] * 9363) >> 16;
        xj[nj] = jv[nj] - yj[nj] * 7;
    }
    float rsc[4][4];
#pragma unroll
    for (int mi = 0; mi < 4; mi++) {
#pragma unroll
        for (int r = 0; r < 4; r++) {
            const int i = mi * 16 + G * 4 + r;
            const int yi = (i * 9363) >> 16;
            const int xi = i - yi * 7;
            float mx = -1e30f;
            float vals[4];
#pragma unroll
            for (int nj = 0; nj < 4; nj++) {
                const bool valid = (i < 49) && (jv[nj] < 49);
                const int bidx = valid ? ((yj[nj] - yi + 6) * 13 + (xj[nj] - xi + 6)) : 0;
                float val = s[mi][nj][r] * SCALE + pes[bidx];
                const bool dead = (!valid) || (ulm && ((yi >= 4) != (yj[nj] >= 4)))
                                           || (lrm && ((xi >= 4) != (xj[nj] >= 4)));
                vals[nj] = dead ? -1e30f : val;
                mx = fmaxf(mx, vals[nj]);
            }
#pragma unroll
            for (int m2 = 1; m2 < 16; m2 <<= 1) mx = fmaxf(mx, __shfl_xor(mx, m2));
            float sum = 0.f;
#pragma unroll
            for (int nj = 0; nj < 4; nj++) {
                const float e = __expf(vals[nj] - mx);
                s[mi][nj][r] = e;
                sum += e;
            }
#pragma unroll
            for (int m2 = 1; m2 < 16; m2 <<= 1) sum += __shfl_xor(sum, m2);
            rsc[mi][r] = 1.0f / sum;
        }
    }

    // ---- P -> LDS (bf16, swizzled row-major [i][j]) ----
#pragma unroll
    for (int mi = 0; mi < 4; mi++)
#pragma unroll
        for (int r = 0; r < 4; r++) {
            const int i = mi * 16 + G * 4 + r;
            const int swz = (i & 7) << 4;
#pragma unroll
            for (int nj = 0; nj < 4; nj++)
                *(unsigned short*)&Pl[wid][i * 128 + ((jv[nj] * 2) ^ swz)] = f2bf(s[mi][nj][r]);
        }

    // ---- PV ----
    f32x4 o[4][2];
#pragma unroll
    for (int mi = 0; mi < 4; mi++)
#pragma unroll
        for (int ni = 0; ni < 2; ni++) o[mi][ni] = zc;
#pragma unroll
    for (int ks = 0; ks < 2; ks++) {
        bf16x8 pa[4];
#pragma unroll
        for (int mi = 0; mi < 4; mi++) {
            const int i = mi * 16 + l16;
            pa[mi] = *(const bf16x8*)&Pl[wid][i * 128 + ((ks * 64 + G * 16) ^ ((i & 7) << 4))];
        }
#pragma unroll
        for (int ni = 0; ni < 2; ni++) {
            const int d = ni * 16 + l16;
            bf16x8 vf = *(const bf16x8*)&Vl[wid][d * 128 + ((ks * 64 + G * 16) ^ ((d & 7) << 4))];
#pragma unroll
            for (int mi = 0; mi < 4; mi++)
                o[mi][ni] = __builtin_amdgcn_mfma_f32_16x16x32_bf16(pa[mi], vf, o[mi][ni], 0, 0, 0);
        }
    }

    // ---- store in FINAL pixel order (fused roll(+3,+3)) ----
#pragma unroll
    for (int mi = 0; mi < 4; mi++)
#pragma unroll
        for (int r = 0; r < 4; r++) {
            const int i = mi * 16 + G * 4 + r;
            if (i < 49) {
                const int yi = (i * 9363) >> 16;
                const int xi = i - yi * 7;
                int hf = wh * 7 + yi + 3; if (hf >= 56) hf -= 56;
                int wf = ww * 7 + xi + 3; if (wf >= 56) wf -= 56;
                const size_t orow = ((size_t)b * PIX + hf * 56 + wf) * 192 + head * 32;
                const float rs = rsc[mi][r];
#pragma unroll
                for (int ni = 0; ni < 2; ni++)
                    ao[orow + ni * 16 + l16] = f2bf(o[mi][ni][r] * rs);
            }
        }
}

// ---------------------------------------------------------------------------
// Kernel C: out-proj GEMM + bias via MFMA. A = attention out (bf16, already in
// final pixel order -> pure linear rows). N=192 in 3 tiles of 64. fp32 out.
// ---------------------------------------------------------------------------
__global__ __launch_bounds__(256) void proj_mfma(
        const unsigned short* __restrict__ ain, const float* __restrict__ wout,
        const float* __restrict__ bout, float* __restrict__ out) {
    __shared__ __align__(16) unsigned char Al[128 * 384];
    __shared__ __align__(16) unsigned char Bl[64 * 384];
    __shared__ float bls[192];
    const int tid = threadIdx.x;
    const int lane = tid & 63, wid = tid >> 6;
    const int G = lane >> 4, l16 = lane & 15;
    const int row0 = blockIdx.x * 128;
    if (tid < 192) bls[tid] = bout[tid];

    {   // stage A (bf16 linear rows, swizzled)
        const int r = tid >> 1, half = tid & 1;
        const unsigned short* src = ain + (size_t)(row0 + r) * 192 + half * 96;
        const int swz = (r & 7) << 4;
#pragma unroll
        for (int c = 0; c < 12; c++) {
            u16x8 v = *(const u16x8*)(src + c * 8);
            const int off = half * 192 + c * 16;
            *(u16x8*)&Al[r * 384 + (off ^ swz)] = v;
        }
    }

    const int wr = wid >> 1, wc = wid & 1;
    f32x4 acc[4][2];
#pragma unroll
    for (int a = 0; a < 4; a++)
#pragma unroll
        for (int bb = 0; bb < 2; bb++) acc[a][bb] = (f32x4){0.f, 0.f, 0.f, 0.f};
    bf16x8 areg[4][6];

    for (int nt = 0; nt < 3; nt++) {
        __syncthreads();
        {   // stage B: wout rows [nt*64, +64) fp32 -> bf16
            const int rB = tid >> 2, q4 = tid & 3;
            const float* src = wout + (size_t)(nt * 64 + rB) * 192 + q4 * 48;
            const int swz = (rB & 7) << 4;
#pragma unroll
            for (int c = 0; c < 6; c++) {
                float4 f0 = *(const float4*)(src + c * 8);
                float4 f1 = *(const float4*)(src + c * 8 + 4);
                const int off = q4 * 96 + c * 16;
                *(u16x8*)&Bl[rB * 384 + (off ^ swz)] = packbf(f0, f1);
            }
        }
        __syncthreads();
        if (nt == 0) {
#pragma unroll
            for (int mi = 0; mi < 4; mi++) {
                const int rr = wr * 64 + mi * 16 + l16;
                const int swz = (rr & 7) << 4;
#pragma unroll
                for (int ks = 0; ks < 6; ks++)
                    areg[mi][ks] = *(const bf16x8*)&Al[rr * 384 + ((ks * 64 + G * 16) ^ swz)];
            }
        }
#pragma unroll
        for (int ks = 0; ks < 6; ks++) {
#pragma unroll
            for (int ni = 0; ni < 2; ni++) {
                const int rb = wc * 32 + ni * 16 + l16;
                bf16x8 bf = *(const bf16x8*)&Bl[rb * 384 + ((ks * 64 + G * 16) ^ ((rb & 7) << 4))];
#pragma unroll
                for (int mi = 0; mi < 4; mi++)
                    acc[mi][ni] = __builtin_amdgcn_mfma_f32_16x16x32_bf16(
                        areg[mi][ks], bf, acc[mi][ni], 0, 0, 0);
            }
        }
#pragma unroll
        for (int mi = 0; mi < 4; mi++) {
#pragma unroll
            for (int ni = 0; ni < 2; ni++) {
                const int n = nt * 64 + wc * 32 + ni * 16 + l16;
                const float bias = bls[n];
#pragma unroll
                for (int r = 0; r < 4; r++) {
                    const int rm = row0 + wr * 64 + mi * 16 + G * 4 + r;
                    out[(size_t)rm * 192 + n] = acc[mi][ni][r] + bias;
                    acc[mi][ni][r] = 0.f;
                }
            }
        }
    }
}

// ---------------------------------------------------------------------------
extern "C" void kernel_launch(void* const* d_in, const int* in_sizes, int n_in,
                              void* d_out, int out_size, void* d_ws, size_t ws_size,
                              hipStream_t stream) {
    const float* x = (const float*)d_in[0];
    const float* wqkv = (const float*)d_in[1];
    const float* pe = (const float*)d_in[2];
    const float* wout = (const float*)d_in[3];
    const float* bout = (const float*)d_in[4];
    (void)in_sizes; (void)n_in; (void)out_size; (void)ws_size;

    const size_t per = (size_t)19267584;  // 32*6*3136*32
    unsigned short* q = (unsigned short*)d_ws;
    unsigned short* k = q + per;
    unsigned short* v = k + per;
    unsigned short* ao = v + per;

    qkv_mfma<<<784, 256, 0, stream>>>(x, wqkv, q, k, v);
    attn_mfma<<<3072, 256, 0, stream>>>(q, k, v, pe, ao);
    proj_mfma<<<784, 256, 0, stream>>>(ao, wout, bout, (float*)d_out);
}

// Round 3
// 283.531 us; speedup vs baseline: 2.3247x; 1.0555x over previous
//
#include <hip/hip_runtime.h>
#include <hip/hip_bf16.h>

#define PIX 3136
#define SCALE 0.17677669529663687f

typedef __attribute__((ext_vector_type(8))) short bf16x8;
typedef __attribute__((ext_vector_type(4))) float f32x4;
typedef __attribute__((ext_vector_type(8))) unsigned short u16x8;

__device__ __forceinline__ unsigned short f2bf(float f) {
    __hip_bfloat16 h = __float2bfloat16(f);
    return *reinterpret_cast<unsigned short*>(&h);
}
__device__ __forceinline__ u16x8 packbf(float4 a, float4 b) {
    u16x8 r;
    r[0] = f2bf(a.x); r[1] = f2bf(a.y); r[2] = f2bf(a.z); r[3] = f2bf(a.w);
    r[4] = f2bf(b.x); r[5] = f2bf(b.y); r[6] = f2bf(b.z); r[7] = f2bf(b.w);
    return r;
}

// ---------------------------------------------------------------------------
// Pre-kernel: convert wqkv (576x192) and wout (192x192) fp32 -> bf16 once.
// ---------------------------------------------------------------------------
__global__ __launch_bounds__(256) void convw(
        const float* __restrict__ wqkv, const float* __restrict__ wout,
        unsigned short* __restrict__ wqb, unsigned short* __restrict__ wob) {
    const int t = blockIdx.x * 256 + threadIdx.x;   // 0..18431
    if (t < 13824) {                                 // 110592/8
        const float* s = wqkv + (size_t)t * 8;
        float4 a = *(const float4*)s, b = *(const float4*)(s + 4);
        *(u16x8*)(wqb + (size_t)t * 8) = packbf(a, b);
    } else {
        const int u = t - 13824;                     // < 4608 = 36864/8
        const float* s = wout + (size_t)u * 8;
        float4 a = *(const float4*)s, b = *(const float4*)(s + 4);
        *(u16x8*)(wob + (size_t)u * 8) = packbf(a, b);
    }
}

// ---------------------------------------------------------------------------
// Fused Swin window-attention block: one block per (batch, window), 6 waves,
// wave h = head h. x -> (roll,-3) -> qkv -> attn(bias+mask+softmax) -> proj
// -> (+bias, roll +3) -> out.  All intermediates in LDS/registers.
// LDS: Axl 24576 (reused as projA) + 6*8704 scratch + pe/bias = 78244 B.
// ---------------------------------------------------------------------------
__global__ __launch_bounds__(384, 3) void fused_swin(
        const float* __restrict__ x, const unsigned short* __restrict__ wq,
        const unsigned short* __restrict__ wo, const float* __restrict__ pe,
        const float* __restrict__ bout, float* __restrict__ out) {
    __shared__ __align__(16) unsigned char Axl[64 * 384];   // x-tile bf16 / projA
    __shared__ __align__(16) unsigned char Scr[6][8704];    // per wave: qk/P + vT
    __shared__ float pes[169];
    __shared__ float bls[192];

    const int tid = threadIdx.x;
    const int lane = tid & 63, h = tid >> 6;    // h = wave = head
    const int G = lane >> 4, l16 = lane & 15;

    const int blk = blockIdx.x;
    const int b = blk >> 6, w = blk & 63;
    const int wh = w >> 3, ww = w & 7;

    if (tid < 169) pes[tid] = pe[tid];
    else if (tid >= 192) bls[tid - 192] = bout[tid - 192];

    // ---- stage rolled x-tile -> Axl bf16 swizzled: rows 0..48 real, 49..63 zero
    {
        const int r = tid / 6, seg = tid % 6;   // 64 rows x 6 segs of 32 floats
        unsigned char* dst = Axl + r * 384;
        const int swz = (r & 7) << 4;
        if (r < 49) {
            const int yi = r / 7, xi = r % 7;
            int sh = wh * 7 + yi + 3; if (sh >= 56) sh -= 56;
            int sw = ww * 7 + xi + 3; if (sw >= 56) sw -= 56;
            const float* src = x + ((size_t)(b * 56 + sh) * 56 + sw) * 192 + seg * 32;
#pragma unroll
            for (int c = 0; c < 4; c++) {
                float4 f0 = *(const float4*)(src + c * 8);
                float4 f1 = *(const float4*)(src + c * 8 + 4);
                const int off = seg * 64 + c * 16;
                *(u16x8*)&dst[off ^ swz] = packbf(f0, f1);
            }
        } else {
            const u16x8 z = {0, 0, 0, 0, 0, 0, 0, 0};
#pragma unroll
            for (int c = 0; c < 4; c++) {
                const int off = seg * 64 + c * 16;
                *(u16x8*)&dst[off ^ swz] = z;
            }
        }
    }
    __syncthreads();

    unsigned char* s0 = Scr[h];          // [64 rows][72 B] qk-scratch, later P-half
    unsigned char* sv = Scr[h] + 4608;   // [32 d][128 B] V^T, swizzled

    const f32x4 zc = (f32x4){0.f, 0.f, 0.f, 0.f};

    // ---- q,k GEMMs for this head (M=64, N=32, K=192), bounce to frags ----
    bf16x8 qf[4], kf[4];
#pragma unroll
    for (int P = 0; P < 2; P++) {
        f32x4 acc[4][2];
#pragma unroll
        for (int mi = 0; mi < 4; mi++) { acc[mi][0] = zc; acc[mi][1] = zc; }
        const unsigned short* wbase = wq + (size_t)(P * 192 + h * 32) * 192;
#pragma unroll
        for (int ks = 0; ks < 6; ks++) {
            bf16x8 b0 = *(const bf16x8*)(wbase + (size_t)l16 * 192 + ks * 32 + G * 8);
            bf16x8 b1 = *(const bf16x8*)(wbase + (size_t)(16 + l16) * 192 + ks * 32 + G * 8);
#pragma unroll
            for (int mi = 0; mi < 4; mi++) {
                const int row = mi * 16 + l16;
                bf16x8 af = *(const bf16x8*)&Axl[row * 384 + ((ks * 64 + G * 16) ^ ((row & 7) << 4))];
                acc[mi][0] = __builtin_amdgcn_mfma_f32_16x16x32_bf16(af, b0, acc[mi][0], 0, 0, 0);
                acc[mi][1] = __builtin_amdgcn_mfma_f32_16x16x32_bf16(af, b1, acc[mi][1], 0, 0, 0);
            }
        }
        // C-layout -> scratch rows (72 B stride: conflict-free scalar writes)
#pragma unroll
        for (int mi = 0; mi < 4; mi++)
#pragma unroll
            for (int ni = 0; ni < 2; ni++)
#pragma unroll
                for (int r = 0; r < 4; r++) {
                    const int row = mi * 16 + G * 4 + r;
                    const int d = ni * 16 + l16;
                    *(unsigned short*)&s0[row * 72 + d * 2] = f2bf(acc[mi][ni][r]);
                }
        // read back as A/B fragments (two 8B loads per frag; 72B rows)
#pragma unroll
        for (int mi = 0; mi < 4; mi++) {
            const int a = (mi * 16 + l16) * 72 + G * 16;
            union { uint2 u[2]; bf16x8 f; } t;
            t.u[0] = *(const uint2*)&s0[a];
            t.u[1] = *(const uint2*)&s0[a + 8];
            if (P == 0) qf[mi] = t.f; else kf[mi] = t.f;
        }
    }

    // ---- QK^T (16 MFMA) ----
    f32x4 s[4][4];
#pragma unroll
    for (int mi = 0; mi < 4; mi++)
#pragma unroll
        for (int nj = 0; nj < 4; nj++)
            s[mi][nj] = __builtin_amdgcn_mfma_f32_16x16x32_bf16(qf[mi], kf[nj], zc, 0, 0, 0);

    // ---- bias + shift-masks + row softmax ----
    const bool ulm = (wh == 7), lrm = (ww == 7);
    int jv[4], yj[4], xj[4];
#pragma unroll
    for (int nj = 0; nj < 4; nj++) {
        jv[nj] = nj * 16 + l16;
        yj[nj] = (jv[nj] * 9363) >> 16;
        xj[nj] = jv[nj] - yj[nj] * 7;
    }
    float rsc[4][4];
#pragma unroll
    for (int mi = 0; mi < 4; mi++) {
#pragma unroll
        for (int r = 0; r < 4; r++) {
            const int i = mi * 16 + G * 4 + r;
            const int yi = (i * 9363) >> 16;
            const int xi = i - yi * 7;
            float mx = -1e30f;
            float vals[4];
#pragma unroll
            for (int nj = 0; nj < 4; nj++) {
                const bool valid = (i < 49) && (jv[nj] < 49);
                const int bidx = valid ? ((yj[nj] - yi + 6) * 13 + (xj[nj] - xi + 6)) : 0;
                float val = s[mi][nj][r] * SCALE + pes[bidx];
                const bool dead = (!valid) || (ulm && ((yi >= 4) != (yj[nj] >= 4)))
                                           || (lrm && ((xi >= 4) != (xj[nj] >= 4)));
                vals[nj] = dead ? -1e30f : val;
                mx = fmaxf(mx, vals[nj]);
            }
#pragma unroll
            for (int m2 = 1; m2 < 16; m2 <<= 1) mx = fmaxf(mx, __shfl_xor(mx, m2));
            float sum = 0.f;
#pragma unroll
            for (int nj = 0; nj < 4; nj++) {
                const float e = __expf(vals[nj] - mx);
                s[mi][nj][r] = e;
                sum += e;
            }
#pragma unroll
            for (int m2 = 1; m2 < 16; m2 <<= 1) sum += __shfl_xor(sum, m2);
            rsc[mi][r] = 1.0f / sum;
        }
    }

    // ---- v GEMM + transposed store into vT ----
    {
        f32x4 acc[4][2];
#pragma unroll
        for (int mi = 0; mi < 4; mi++) { acc[mi][0] = zc; acc[mi][1] = zc; }
        const unsigned short* wbase = wq + (size_t)(384 + h * 32) * 192;
#pragma unroll
        for (int ks = 0; ks < 6; ks++) {
            bf16x8 b0 = *(const bf16x8*)(wbase + (size_t)l16 * 192 + ks * 32 + G * 8);
            bf16x8 b1 = *(const bf16x8*)(wbase + (size_t)(16 + l16) * 192 + ks * 32 + G * 8);
#pragma unroll
            for (int mi = 0; mi < 4; mi++) {
                const int row = mi * 16 + l16;
                bf16x8 af = *(const bf16x8*)&Axl[row * 384 + ((ks * 64 + G * 16) ^ ((row & 7) << 4))];
                acc[mi][0] = __builtin_amdgcn_mfma_f32_16x16x32_bf16(af, b0, acc[mi][0], 0, 0, 0);
                acc[mi][1] = __builtin_amdgcn_mfma_f32_16x16x32_bf16(af, b1, acc[mi][1], 0, 0, 0);
            }
        }
        // vT[d][j] swizzled; rows j>=49 are genuine zeros (Axl zero rows)
#pragma unroll
        for (int mi = 0; mi < 4; mi++)
#pragma unroll
            for (int ni = 0; ni < 2; ni++)
#pragma unroll
                for (int r = 0; r < 4; r++) {
                    const int j = mi * 16 + G * 4 + r;
                    const int d = ni * 16 + l16;
                    *(unsigned short*)&sv[d * 128 + ((j * 2) ^ ((d & 7) << 4))] = f2bf(acc[mi][ni][r]);
                }
    }

    // ---- PV: two K-halves through the P bounce (reuses qk-scratch) ----
    f32x4 o[4][2];
#pragma unroll
    for (int mi = 0; mi < 4; mi++) { o[mi][0] = zc; o[mi][1] = zc; }
#pragma unroll
    for (int ks = 0; ks < 2; ks++) {
#pragma unroll
        for (int mi = 0; mi < 4; mi++)
#pragma unroll
            for (int r = 0; r < 4; r++) {
                const int row = mi * 16 + G * 4 + r;
#pragma unroll
                for (int njh = 0; njh < 2; njh++) {
                    const int nj = ks * 2 + njh;
                    *(unsigned short*)&s0[row * 72 + (njh * 16 + l16) * 2] = f2bf(s[mi][nj][r]);
                }
            }
        bf16x8 pa[4];
#pragma unroll
        for (int mi = 0; mi < 4; mi++) {
            const int a = (mi * 16 + l16) * 72 + G * 16;
            union { uint2 u[2]; bf16x8 f; } t;
            t.u[0] = *(const uint2*)&s0[a];
            t.u[1] = *(const uint2*)&s0[a + 8];
            pa[mi] = t.f;
        }
#pragma unroll
        for (int ni = 0; ni < 2; ni++) {
            const int d = ni * 16 + l16;
            bf16x8 vf = *(const bf16x8*)&sv[d * 128 + ((ks * 64 + G * 16) ^ ((d & 7) << 4))];
#pragma unroll
            for (int mi = 0; mi < 4; mi++)
                o[mi][ni] = __builtin_amdgcn_mfma_f32_16x16x32_bf16(pa[mi], vf, o[mi][ni], 0, 0, 0);
        }
    }

    // ---- attention-out -> projA (reuse Axl; all Axl reads are done) ----
    __syncthreads();
#pragma unroll
    for (int mi = 0; mi < 4; mi++)
#pragma unroll
        for (int ni = 0; ni < 2; ni++)
#pragma unroll
            for (int r = 0; r < 4; r++) {
                const int i = mi * 16 + G * 4 + r;
                const int col = h * 32 + ni * 16 + l16;
                *(unsigned short*)&Axl[i * 384 + ((col * 2) ^ ((i & 7) << 4))] =
                    f2bf(o[mi][ni][r] * rsc[mi][r]);
            }
    __syncthreads();

    // ---- out-proj GEMM (M=64, N=32 cols of 192 per wave, K=192) + bias ----
    {
        f32x4 acc[4][2];
#pragma unroll
        for (int mi = 0; mi < 4; mi++) { acc[mi][0] = zc; acc[mi][1] = zc; }
        const unsigned short* wbase = wo + (size_t)(h * 32) * 192;
#pragma unroll
        for (int ks = 0; ks < 6; ks++) {
            bf16x8 b0 = *(const bf16x8*)(wbase + (size_t)l16 * 192 + ks * 32 + G * 8);
            bf16x8 b1 = *(const bf16x8*)(wbase + (size_t)(16 + l16) * 192 + ks * 32 + G * 8);
#pragma unroll
            for (int mi = 0; mi < 4; mi++) {
                const int row = mi * 16 + l16;
                bf16x8 af = *(const bf16x8*)&Axl[row * 384 + ((ks * 64 + G * 16) ^ ((row & 7) << 4))];
                acc[mi][0] = __builtin_amdgcn_mfma_f32_16x16x32_bf16(af, b0, acc[mi][0], 0, 0, 0);
                acc[mi][1] = __builtin_amdgcn_mfma_f32_16x16x32_bf16(af, b1, acc[mi][1], 0, 0, 0);
            }
        }
        const float bia0 = bls[h * 32 + l16];
        const float bia1 = bls[h * 32 + 16 + l16];
#pragma unroll
        for (int mi = 0; mi < 4; mi++)
#pragma unroll
            for (int r = 0; r < 4; r++) {
                const int i = mi * 16 + G * 4 + r;
                if (i < 49) {
                    const int yi = (i * 9363) >> 16;
                    const int xi = i - yi * 7;
                    int hf = wh * 7 + yi + 3; if (hf >= 56) hf -= 56;
                    int wf = ww * 7 + xi + 3; if (wf >= 56) wf -= 56;
                    float* orow = out + ((size_t)(b * PIX) + hf * 56 + wf) * 192 + h * 32;
                    orow[l16] = acc[mi][0][r] + bia0;
                    orow[16 + l16] = acc[mi][1][r] + bia1;
                }
            }
    }
}

// ---------------------------------------------------------------------------
extern "C" void kernel_launch(void* const* d_in, const int* in_sizes, int n_in,
                              void* d_out, int out_size, void* d_ws, size_t ws_size,
                              hipStream_t stream) {
    const float* x = (const float*)d_in[0];
    const float* wqkv = (const float*)d_in[1];
    const float* pe = (const float*)d_in[2];
    const float* wout = (const float*)d_in[3];
    const float* bout = (const float*)d_in[4];
    (void)in_sizes; (void)n_in; (void)out_size; (void)ws_size;

    unsigned short* wqb = (unsigned short*)d_ws;            // 110592 bf16
    unsigned short* wob = wqb + 110592;                     // 36864 bf16

    convw<<<72, 256, 0, stream>>>(wqkv, wout, wqb, wob);
    fused_swin<<<2048, 384, 0, stream>>>(x, wqb, wob, pe, bout, (float*)d_out);
}